// Round 14
// baseline (32.125 us; speedup 1.0000x reference)
//
#include <hip/hip_runtime.h>
#include <hip/hip_fp16.h>
#include <math.h>

#define NPTS    32
#define UNITS   64
#define PTOT    40000
#define NPAIRS  (PTOT / 2)          // 20000
#define SBLOCKS 2500
#define WPB     4                   // waves per block (256 threads)
#define TOTW    (SBLOCKS * WPB)     // 10000 waves
#define PPW     (NPAIRS / TOTW)     // 2 pairs per wave (exact)
#define NSLOTS  16                  // partial-merge slots (atomicAdd fan-in ~156/addr)

// x[p,n,u] = b[p,u] + core(n,u),  core = f0*wp0 + f1*wp1 + f2*wp2 + f3*wp3.
// BIAS HOISTED out of the loop: the inner loop accumulates core-only
//   sum_core, sq_core, max_core  (per pillar), and afterwards
//   Σx  = sum_core + nv*b
//   Σx² = sq_core + 2b*sum_core + nv*b²
//   max(x) = max_core + b
// so the butterfly/means/coors/bias dependency chain overlaps the loop
// instead of serializing before it.
// sg = sign(gamma[u]) folded into wp/w: chain yields x' = sg*x; the padded-row
// candidate (0) is folded into max when nv<32 -> apply is a pure stream:
// out = relu(|scale|*ext + shift), shift = beta - mean'*|scale|.
// Point broadcast via wave-uniform s_load. xext fp16. 16-slot atomic merge.

__global__ __launch_bounds__(256)
void pfn_main(const float* __restrict__ feat,
              const int*   __restrict__ nvox,
              const int*   __restrict__ coors,
              const float* __restrict__ Wm,
              const float* __restrict__ gamma,
              __half*      __restrict__ xext,
              float*       __restrict__ slots)
{
    __shared__ float ps[WPB][128];

    const int tid  = threadIdx.x;
    const int lane = tid & 63;
    const int wave = __builtin_amdgcn_readfirstlane(tid >> 6);
    const int gwave = blockIdx.x * WPB + wave;

    const float sg  = (gamma[lane] >= 0.f) ? 1.f : -1.f;
    const float w4 = sg * Wm[4 * UNITS + lane], w5 = sg * Wm[5 * UNITS + lane];
    const float w6 = sg * Wm[6 * UNITS + lane], w7 = sg * Wm[7 * UNITS + lane];
    const float w8 = sg * Wm[8 * UNITS + lane];
    const float wp0 = sg * Wm[0 * UNITS + lane] + w4 + w7;
    const float wp1 = sg * Wm[1 * UNITS + lane] + w5 + w8;
    const float wp2 = sg * Wm[2 * UNITS + lane] + w6;
    const float wp3 = sg * Wm[3 * UNITS + lane];

    float lsum = 0.f, lsq = 0.f;   // sums of x' = sg*x over valid points

    #pragma unroll
    for (int it = 0; it < PPW; ++it) {
        const int pair = it * TOTW + gwave;   // uniform
        const int p0 = pair * 2;              // uniform

        // issue the coalesced vector load now; its result (butterfly) is
        // consumed only AFTER the core loop -> latency overlapped
        const float4 f4 = *reinterpret_cast<const float4*>(feat + (size_t)pair * 256 + lane * 4);

        int nvA = nvox[p0], nvB = nvox[p0 + 1];       // uniform -> s_load (loop bound)
        nvA = nvA < 1 ? 1 : (nvA > NPTS ? NPTS : nvA);
        nvB = nvB < 1 ? 1 : (nvB > NPTS ? NPTS : nvB);

        // uniform point bases: whole wave reads the same point -> s_load
        const float* fpA = feat + (size_t)p0 * 128;
        const float* fpB = fpA + 128;

        // core-only accumulators (bias applied post-loop)
        float sA = 0.f, sB = 0.f, qA = 0.f, qB = 0.f;
        float mxA = -3.4e38f, mxB = -3.4e38f;
        const int nmin = nvA < nvB ? nvA : nvB;

        #pragma unroll 8
        for (int n = 0; n < nmin; ++n) {
            const float4 a  = *reinterpret_cast<const float4*>(fpA + n * 4);
            const float4 b4 = *reinterpret_cast<const float4*>(fpB + n * 4);
            const float xA = fmaf(a.x,  wp0, fmaf(a.y,  wp1, fmaf(a.z,  wp2, a.w  * wp3)));
            const float xB = fmaf(b4.x, wp0, fmaf(b4.y, wp1, fmaf(b4.z, wp2, b4.w * wp3)));
            sA += xA; qA = fmaf(xA, xA, qA); mxA = fmaxf(mxA, xA);
            sB += xB; qB = fmaf(xB, xB, qB); mxB = fmaxf(mxB, xB);
        }
        #pragma unroll 4
        for (int n = nmin; n < nvA; ++n) {            // at most one tail loop runs
            const float4 a = *reinterpret_cast<const float4*>(fpA + n * 4);
            const float xA = fmaf(a.x, wp0, fmaf(a.y, wp1, fmaf(a.z, wp2, a.w * wp3)));
            sA += xA; qA = fmaf(xA, xA, qA); mxA = fmaxf(mxA, xA);
        }
        #pragma unroll 4
        for (int n = nmin; n < nvB; ++n) {
            const float4 b4 = *reinterpret_cast<const float4*>(fpB + n * 4);
            const float xB = fmaf(b4.x, wp0, fmaf(b4.y, wp1, fmaf(b4.z, wp2, b4.w * wp3)));
            sB += xB; qB = fmaf(xB, xB, qB); mxB = fmaxf(mxB, xB);
        }

        // ---- post-loop: butterfly + means + bias (overlapped latency) ----
        float sx = f4.x, sy = f4.y, sz = f4.z;
        #pragma unroll
        for (int off = 1; off < 32; off <<= 1) {
            sx += __shfl_xor(sx, off);
            sy += __shfl_xor(sy, off);
            sz += __shfl_xor(sz, off);
        }
        const float cxA = (float)coors[p0 * 4 + 3] * 0.2f + 0.1f;
        const float cyA = (float)coors[p0 * 4 + 2] * 0.2f + (-39.9f);
        const float cxB = (float)coors[p0 * 4 + 7] * 0.2f + 0.1f;
        const float cyB = (float)coors[p0 * 4 + 6] * 0.2f + (-39.9f);
        const float iA  = 1.f / (float)nvA,  iB  = 1.f / (float)nvB;
        const float mA0 = __shfl(sx, 0)  * iA, mA1 = __shfl(sy, 0)  * iA, mA2 = __shfl(sz, 0)  * iA;
        const float mB0 = __shfl(sx, 32) * iB, mB1 = __shfl(sy, 32) * iB, mB2 = __shfl(sz, 32) * iB;
        const float bA = -(mA0 * w4 + mA1 * w5 + mA2 * w6 + cxA * w7 + cyA * w8);
        const float bB = -(mB0 * w4 + mB1 * w5 + mB2 * w6 + cxB * w7 + cyB * w8);

        // bias fixup:  Σx = s + nv*b ;  Σx² = q + 2b*s + nv*b² ;  max = mx + b
        lsum += fmaf((float)nvA, bA, sA) + fmaf((float)nvB, bB, sB);
        lsq  += qA + fmaf(2.f * bA, sA, (float)nvA * bA * bA)
              + qB + fmaf(2.f * bB, sB, (float)nvB * bB * bB);
        float mA = mxA + bA, mB = mxB + bB;
        if (nvA < NPTS) mA = fmaxf(mA, 0.f);          // padded-row candidate
        if (nvB < NPTS) mB = fmaxf(mB, 0.f);

        xext[(size_t)p0 * UNITS + lane]       = __float2half_rn(mA);   // max(x')
        xext[(size_t)(p0 + 1) * UNITS + lane] = __float2half_rn(mB);
    }

    ps[wave][lane]      = lsum;    // sums of x' ; x'^2 == x^2
    ps[wave][64 + lane] = lsq;
    __syncthreads();
    if (tid < 128) {
        const float v = ps[0][tid] + ps[1][tid] + ps[2][tid] + ps[3][tid];
        atomicAdd(&slots[(blockIdx.x & (NSLOTS - 1)) * 128 + tid], v);  // ~156 RMW/addr
    }
}

// Apply: per-block BN finalize from the 16x128 slot array (8 KB, L2-hot),
// then pure stream: out = relu(|scale|*ext + shift). No nvox logic.
#define CBLOCKS 2500   // 2500*256 threads * 4 units = 2,560,000 floats exactly

__global__ __launch_bounds__(256)
void pfn_apply(const float*  __restrict__ slots,
               const float*  __restrict__ gamma,
               const float*  __restrict__ beta,
               const __half2* __restrict__ xext2,
               float4*       __restrict__ out)
{
    __shared__ __align__(16) float s_sc[64], s_sh[64];
    const int t = threadIdx.x;
    if (t < 64) {
        float S = 0.f, Q = 0.f;
        #pragma unroll
        for (int s = 0; s < NSLOTS; ++s) {
            S += slots[s * 128 + t];
            Q += slots[s * 128 + 64 + t];
        }
        const float INV_PN = 1.0f / (float)(PTOT * NPTS);
        const float mean = S * INV_PN;
        const float var  = Q * INV_PN - mean * mean;
        const float absc = fabsf(gamma[t]) * rsqrtf(var + 1e-3f);
        s_sc[t] = absc;
        s_sh[t] = beta[t] - mean * absc;
    }
    __syncthreads();

    const int i  = blockIdx.x * 256 + t;             // quad index (4 units)
    const int u0 = (i & 15) * 4;                     // first unit of this quad
    const float4 sc = *reinterpret_cast<const float4*>(&s_sc[u0]);
    const float4 sh = *reinterpret_cast<const float4*>(&s_sh[u0]);
    const float2 e01 = __half22float2(xext2[2 * i]);
    const float2 e23 = __half22float2(xext2[2 * i + 1]);
    float4 o;
    o.x = fmaxf(fmaf(e01.x, sc.x, sh.x), 0.f);
    o.y = fmaxf(fmaf(e01.y, sc.y, sh.y), 0.f);
    o.z = fmaxf(fmaf(e23.x, sc.z, sh.z), 0.f);
    o.w = fmaxf(fmaf(e23.y, sc.w, sh.w), 0.f);
    out[i] = o;
}

extern "C" void kernel_launch(void* const* d_in, const int* in_sizes, int n_in,
                              void* d_out, int out_size, void* d_ws, size_t ws_size,
                              hipStream_t stream)
{
    const float* feat  = (const float*)d_in[0];
    const int*   nvox  = (const int*)d_in[1];
    const int*   coors = (const int*)d_in[2];
    const float* Wm    = (const float*)d_in[3];
    const float* gamma = (const float*)d_in[4];
    const float* beta  = (const float*)d_in[5];
    float* out = (float*)d_out;

    __half* xext  = (__half*)d_ws;                          // P*U halves = 5.12 MB
    float*  slots = (float*)(xext + (size_t)PTOT * UNITS);  // NSLOTS*128 floats = 8 KB

    hipMemsetAsync(slots, 0, NSLOTS * 128 * sizeof(float), stream);  // ws not re-zeroed by harness
    pfn_main<<<SBLOCKS, 256, 0, stream>>>(feat, nvox, coors, Wm, gamma, xext, slots);
    pfn_apply<<<CBLOCKS, 256, 0, stream>>>(slots, gamma, beta,
                                           (const __half2*)xext, (float4*)out);
}

// Round 15
// 29.297 us; speedup vs baseline: 1.0965x; 1.0965x over previous
//
#include <hip/hip_runtime.h>
#include <hip/hip_fp16.h>
#include <math.h>

#define NPTS    32
#define UNITS   64
#define PTOT    40000
#define NPAIRS  (PTOT / 2)          // 20000
#define SBLOCKS 2500
#define WPB     4                   // waves per block (256 threads)
#define TOTW    (SBLOCKS * WPB)     // 10000 waves
#define PPW     (NPAIRS / TOTW)     // 2 pairs per wave (exact)
#define NSLOTS  16                  // partial-merge slots (atomicAdd fan-in ~156/addr)

// x[p,n,u] = b[p,u] + f0*wp0 + f1*wp1 + f2*wp2 + f3*wp3  (per lane = unit)
// wp folds W rows: wp0=W0+W4+W7, wp1=W1+W5+W8, wp2=W2+W6, wp3=W3
// b = -(m0*W4 + m1*W5 + m2*W6 + cx*W7 + cy*W8)
// sg = sign(gamma[u]) folded: chain yields x' = sg*x; max(x') over valid
// points with the padded-row candidate (0) folded in when nv<32 -> apply is
// a pure stream: out = relu(|scale|*ext + shift), shift = beta - mean'*|scale|.
// Point broadcast via wave-uniform s_load (best measured mechanism, R4/R11).
// xext stored fp16 (|x'| small; rel-err 2^-11 << 0.166 threshold).
// Stats: per-block LDS reduce -> 16-slot atomicAdd merge (no finalize kernel).

__global__ __launch_bounds__(256)
void pfn_main(const float* __restrict__ feat,
              const int*   __restrict__ nvox,
              const int*   __restrict__ coors,
              const float* __restrict__ Wm,
              const float* __restrict__ gamma,
              __half*      __restrict__ xext,
              float*       __restrict__ slots)
{
    __shared__ float ps[WPB][128];

    const int tid  = threadIdx.x;
    const int lane = tid & 63;
    const int wave = __builtin_amdgcn_readfirstlane(tid >> 6);
    const int gwave = blockIdx.x * WPB + wave;

    const float sg  = (gamma[lane] >= 0.f) ? 1.f : -1.f;
    const float w4 = sg * Wm[4 * UNITS + lane], w5 = sg * Wm[5 * UNITS + lane];
    const float w6 = sg * Wm[6 * UNITS + lane], w7 = sg * Wm[7 * UNITS + lane];
    const float w8 = sg * Wm[8 * UNITS + lane];
    const float wp0 = sg * Wm[0 * UNITS + lane] + w4 + w7;
    const float wp1 = sg * Wm[1 * UNITS + lane] + w5 + w8;
    const float wp2 = sg * Wm[2 * UNITS + lane] + w6;
    const float wp3 = sg * Wm[3 * UNITS + lane];

    float lsum = 0.f, lsq = 0.f;   // sums of x' = sg*x over valid points

    #pragma unroll
    for (int it = 0; it < PPW; ++it) {
        const int pair = it * TOTW + gwave;   // uniform
        const int p0 = pair * 2;              // uniform

        // coalesced vector load (1 KB/wave) for the points-mean butterfly
        const float4 f4 = *reinterpret_cast<const float4*>(feat + (size_t)pair * 256 + lane * 4);
        float sx = f4.x, sy = f4.y, sz = f4.z;
        #pragma unroll
        for (int off = 1; off < 32; off <<= 1) {
            sx += __shfl_xor(sx, off);
            sy += __shfl_xor(sy, off);
            sz += __shfl_xor(sz, off);
        }

        int nvA = nvox[p0], nvB = nvox[p0 + 1];       // uniform -> s_load
        nvA = nvA < 1 ? 1 : (nvA > NPTS ? NPTS : nvA);
        nvB = nvB < 1 ? 1 : (nvB > NPTS ? NPTS : nvB);
        const float cxA = (float)coors[p0 * 4 + 3] * 0.2f + 0.1f;
        const float cyA = (float)coors[p0 * 4 + 2] * 0.2f + (-39.9f);
        const float cxB = (float)coors[p0 * 4 + 7] * 0.2f + 0.1f;
        const float cyB = (float)coors[p0 * 4 + 6] * 0.2f + (-39.9f);
        const float iA  = 1.f / (float)nvA,  iB  = 1.f / (float)nvB;
        const float mA0 = __shfl(sx, 0)  * iA, mA1 = __shfl(sy, 0)  * iA, mA2 = __shfl(sz, 0)  * iA;
        const float mB0 = __shfl(sx, 32) * iB, mB1 = __shfl(sy, 32) * iB, mB2 = __shfl(sz, 32) * iB;
        const float bA = -(mA0 * w4 + mA1 * w5 + mA2 * w6 + cxA * w7 + cyA * w8);
        const float bB = -(mB0 * w4 + mB1 * w5 + mB2 * w6 + cxB * w7 + cyB * w8);

        // uniform point bases: whole wave reads the same point -> s_load
        const float* fpA = feat + (size_t)p0 * 128;
        const float* fpB = fpA + 128;

        float mA = -3.4e38f, mB = -3.4e38f;
        const int nmin = nvA < nvB ? nvA : nvB;

        #pragma unroll 4
        for (int n = 0; n < nmin; ++n) {
            const float4 a  = *reinterpret_cast<const float4*>(fpA + n * 4);
            const float4 b4 = *reinterpret_cast<const float4*>(fpB + n * 4);
            const float xA = fmaf(a.x,  wp0, fmaf(a.y,  wp1, fmaf(a.z,  wp2, fmaf(a.w,  wp3, bA))));
            const float xB = fmaf(b4.x, wp0, fmaf(b4.y, wp1, fmaf(b4.z, wp2, fmaf(b4.w, wp3, bB))));
            lsum += xA; lsq = fmaf(xA, xA, lsq); mA = fmaxf(mA, xA);
            lsum += xB; lsq = fmaf(xB, xB, lsq); mB = fmaxf(mB, xB);
        }
        #pragma unroll 4
        for (int n = nmin; n < nvA; ++n) {            // at most one tail loop runs
            const float4 a = *reinterpret_cast<const float4*>(fpA + n * 4);
            const float xA = fmaf(a.x, wp0, fmaf(a.y, wp1, fmaf(a.z, wp2, fmaf(a.w, wp3, bA))));
            lsum += xA; lsq = fmaf(xA, xA, lsq); mA = fmaxf(mA, xA);
        }
        #pragma unroll 4
        for (int n = nmin; n < nvB; ++n) {
            const float4 b4 = *reinterpret_cast<const float4*>(fpB + n * 4);
            const float xB = fmaf(b4.x, wp0, fmaf(b4.y, wp1, fmaf(b4.z, wp2, fmaf(b4.w, wp3, bB))));
            lsum += xB; lsq = fmaf(xB, xB, lsq); mB = fmaxf(mB, xB);
        }

        // fold the padded-row candidate (x'==0) into the max when nv<32
        if (nvA < NPTS) mA = fmaxf(mA, 0.f);          // uniform predicate
        if (nvB < NPTS) mB = fmaxf(mB, 0.f);

        xext[(size_t)p0 * UNITS + lane]       = __float2half_rn(mA);   // max(x')
        xext[(size_t)(p0 + 1) * UNITS + lane] = __float2half_rn(mB);
    }

    ps[wave][lane]      = lsum;    // sums of x' ; x'^2 == x^2
    ps[wave][64 + lane] = lsq;
    __syncthreads();
    if (tid < 128) {
        const float v = ps[0][tid] + ps[1][tid] + ps[2][tid] + ps[3][tid];
        atomicAdd(&slots[(blockIdx.x & (NSLOTS - 1)) * 128 + tid], v);  // ~156 RMW/addr
    }
}

// Apply: per-block BN finalize from the 16x128 slot array (8 KB, L2-hot),
// then pure stream: out = relu(|scale|*ext + shift). No nvox logic.
// 1024-thread blocks: head cost amortized 4x vs 256-thread blocks.
#define CBLOCKS 625   // 625 * 1024 threads * 4 units = 2,560,000 floats exactly

__global__ __launch_bounds__(1024)
void pfn_apply(const float*  __restrict__ slots,
               const float*  __restrict__ gamma,
               const float*  __restrict__ beta,
               const __half2* __restrict__ xext2,
               float4*       __restrict__ out)
{
    __shared__ __align__(16) float s_sc[64], s_sh[64];
    const int t = threadIdx.x;
    if (t < 64) {
        float S = 0.f, Q = 0.f;
        #pragma unroll
        for (int s = 0; s < NSLOTS; ++s) {
            S += slots[s * 128 + t];
            Q += slots[s * 128 + 64 + t];
        }
        // sums are of x' = sg*x: mean'^2 == mean^2, x'^2 == x^2.
        // scale*ext_x = |scale|*max(x'); shift = beta - mean'*|scale|.
        const float INV_PN = 1.0f / (float)(PTOT * NPTS);
        const float mean = S * INV_PN;
        const float var  = Q * INV_PN - mean * mean;
        const float absc = fabsf(gamma[t]) * rsqrtf(var + 1e-3f);
        s_sc[t] = absc;
        s_sh[t] = beta[t] - mean * absc;
    }
    __syncthreads();

    const int i  = blockIdx.x * 1024 + t;            // quad index (4 units)
    const int u0 = (i & 15) * 4;                     // first unit of this quad
    const float4 sc = *reinterpret_cast<const float4*>(&s_sc[u0]);
    const float4 sh = *reinterpret_cast<const float4*>(&s_sh[u0]);
    const float2 e01 = __half22float2(xext2[2 * i]);
    const float2 e23 = __half22float2(xext2[2 * i + 1]);
    float4 o;
    o.x = fmaxf(fmaf(e01.x, sc.x, sh.x), 0.f);
    o.y = fmaxf(fmaf(e01.y, sc.y, sh.y), 0.f);
    o.z = fmaxf(fmaf(e23.x, sc.z, sh.z), 0.f);
    o.w = fmaxf(fmaf(e23.y, sc.w, sh.w), 0.f);
    out[i] = o;
}

extern "C" void kernel_launch(void* const* d_in, const int* in_sizes, int n_in,
                              void* d_out, int out_size, void* d_ws, size_t ws_size,
                              hipStream_t stream)
{
    const float* feat  = (const float*)d_in[0];
    const int*   nvox  = (const int*)d_in[1];
    const int*   coors = (const int*)d_in[2];
    const float* Wm    = (const float*)d_in[3];
    const float* gamma = (const float*)d_in[4];
    const float* beta  = (const float*)d_in[5];
    float* out = (float*)d_out;

    __half* xext  = (__half*)d_ws;                          // P*U halves = 5.12 MB
    float*  slots = (float*)(xext + (size_t)PTOT * UNITS);  // NSLOTS*128 floats = 8 KB

    hipMemsetAsync(slots, 0, NSLOTS * 128 * sizeof(float), stream);  // ws not re-zeroed by harness
    pfn_main<<<SBLOCKS, 256, 0, stream>>>(feat, nvox, coors, Wm, gamma, xext, slots);
    pfn_apply<<<CBLOCKS, 1024, 0, stream>>>(slots, gamma, beta,
                                            (const __half2*)xext, (float4*)out);
}